// Round 4
// baseline (108.416 us; speedup 1.0000x reference)
//
#include <hip/hip_runtime.h>
#include <hip/hip_bf16.h>
#include <stdint.h>

#define NB 2048      // groups
#define D 128
#define NPG 91
#define ROWS 96

typedef __attribute__((ext_vector_type(8))) short short8;
typedef __attribute__((ext_vector_type(4))) float f32x4;

__device__ __forceinline__ unsigned bf16pk(float a, float b) {
  __hip_bfloat162 h2 = __float22bfloat162_rn(make_float2(a, b));
  return *reinterpret_cast<unsigned*>(&h2);   // v_cvt_pk_bf16_f32
}

__device__ __forceinline__ float sigf(float x) {
  float e = __expf(-x);
  return __builtin_amdgcn_rcpf(1.0f + e);     // v_rcp_f32, ~1ulp
}

// K0a: fv[o][b][h] = sum_d feats[last_idx[o][b]][d] * Wv[o][d][h]  + bu[o][h]
__global__ void fv_kernel(const float* __restrict__ feats,
                          const float* __restrict__ Wv,
                          const float* __restrict__ bu,
                          const int* __restrict__ last_idx,
                          float* __restrict__ fv) {
  __shared__ float rows[16][128];
  __shared__ int lidx[16];
  const int o = blockIdx.y;
  const int b0 = blockIdx.x * 16;
  const int t = threadIdx.x;
  if (t < 16) lidx[t] = last_idx[o * NB + b0 + t];
  __syncthreads();
  #pragma unroll
  for (int i = 0; i < 8; ++i) {
    int el = t + i * 256;
    int r = el >> 7, d = el & 127;
    rows[r][d] = feats[(size_t)lidx[r] * D + d];
  }
  __syncthreads();
  const int h = t & 127, half = t >> 7;
  float acc[8];
  #pragma unroll
  for (int j = 0; j < 8; ++j) acc[j] = 0.f;
  const float* wvo = Wv + (size_t)o * D * D + h;
  for (int d0 = 0; d0 < D; d0 += 4) {
    float w0 = wvo[(d0 + 0) * D], w1 = wvo[(d0 + 1) * D];
    float w2 = wvo[(d0 + 2) * D], w3 = wvo[(d0 + 3) * D];
    #pragma unroll
    for (int j = 0; j < 8; ++j) {
      const float4 f = *(const float4*)&rows[half * 8 + j][d0];
      acc[j] += f.x * w0 + f.y * w1 + f.z * w2 + f.w * w3;
    }
  }
  const float bb = bu[o * D + h];
  #pragma unroll
  for (int j = 0; j < 8; ++j)
    fv[((size_t)o * NB + b0 + half * 8 + j) * D + h] = acc[j] + bb;
}

// K0b: pack Wu transposed to bf16 in MFMA B-fragment order:
// wupk[(o*4+kk)*512 + row*4 + g] (uint4) = Wu[o][kk*32+g*8 + 0..7][row] as 8 bf16
__global__ void wut_pack(const float* __restrict__ Wu, uint4* __restrict__ wupk) {
  const int o = blockIdx.x >> 2, kk = blockIdx.x & 3;
  const int t = threadIdx.x;
  #pragma unroll
  for (int i = 0; i < 2; ++i) {
    int idx = i * 256 + t;              // 0..511
    int row = idx >> 2, g = idx & 3;
    const float* src = Wu + (size_t)o * D * D + (kk * 32 + g * 8) * D + row;
    uint4 pk;
    pk.x = bf16pk(src[0 * D], src[1 * D]);
    pk.y = bf16pk(src[2 * D], src[3 * D]);
    pk.z = bf16pk(src[4 * D], src[5 * D]);
    pk.w = bf16pk(src[6 * D], src[7 * D]);
    wupk[(size_t)blockIdx.x * 512 + idx] = pk;
  }
}

// K1: one block per group, 512 threads (8 waves), 4 blocks/CU = 32 waves/CU.
// Wave (wm,wh): M-half wm (3 of 6 M-tiles) x h-slice wh (32 of 128 h).
__global__ __launch_bounds__(512, 8) void sihg_main(
    const float* __restrict__ feats,
    const uint4* __restrict__ wupk,
    const float* __restrict__ We,
    const float* __restrict__ fvb,
    float* __restrict__ out) {
  __shared__ __align__(16) char lds[30336];
  constexpr int A_OFF  = 0;       // bf16 [96][128] swizzled (256B rows); later part[16][384] f32
  constexpr int EP_OFF = 24576;   // float [4][3][96] e-partials (indexed by wh)
  constexpr int AL_OFF = 29184;   // float [3][96]

  const int t = threadIdx.x;
  const int b = blockIdx.x;
  const int w = t >> 6;       // wave 0..7
  const int wh = w & 3;       // h-slice
  const int wm = w >> 2;      // M-half
  const int l = t & 63;
  const int g = l >> 4;
  const int lm = l & 15;

  float (*ep)[3][96] = (float (*)[3][96])(lds + EP_OFF);
  float (*alpha)[96] = (float (*)[96])(lds + AL_OFF);

  const float* fbase = feats + (size_t)b * NPG * D;
  const int h1 = 32 * wh + lm, h2 = 32 * wh + 16 + lm;

  // o=0 B-fragments hoisted above the staging barrier
  short8 bf0[4], bf1[4];
  #pragma unroll
  for (int kk = 0; kk < 4; ++kk) {
    size_t base = (size_t)kk * 512;
    bf0[kk] = *(const short8*)&wupk[base + h1 * 4 + g];
    bf1[kk] = *(const short8*)&wupk[base + h2 * 4 + g];
  }

  // ---- phase 1: feats -> LDS bf16, swizzled; rows 91..95 zero-padded
  #pragma unroll
  for (int i = 0; i < 3; ++i) {
    int c = t + i * 512;              // 1536 chunks of 8 bf16
    int r = c >> 4, d0 = (c & 15) * 8;
    uint4 pk4;
    if (r < NPG) {
      const float* src = fbase + r * D + d0;
      float4 f0 = *(const float4*)(src);
      float4 f1 = *(const float4*)(src + 4);
      pk4.x = bf16pk(f0.x, f0.y);
      pk4.y = bf16pk(f0.z, f0.w);
      pk4.z = bf16pk(f1.x, f1.y);
      pk4.w = bf16pk(f1.z, f1.w);
    } else {
      pk4.x = 0u; pk4.y = 0u; pk4.z = 0u; pk4.w = 0u;
    }
    int off = r * 256 + ((d0 * 2) ^ ((r & 7) << 4));
    *(uint4*)(lds + A_OFF + off) = pk4;
  }
  __syncthreads();

  for (int o = 0; o < 3; ++o) {
    if (o > 0) {
      #pragma unroll
      for (int kk = 0; kk < 4; ++kk) {
        size_t base = (size_t)(o * 4 + kk) * 512;
        bf0[kk] = *(const short8*)&wupk[base + h1 * 4 + g];
        bf1[kk] = *(const short8*)&wupk[base + h2 * 4 + g];
      }
    }
    const float bfva = fvb[((size_t)o * NB + b) * D + h1];
    const float bfvb = fvb[((size_t)o * NB + b) * D + h2];
    const float wea  = We[o * D + h1];
    const float web  = We[o * D + h2];

    #pragma unroll
    for (int mi = 0; mi < 3; ++mi) {
      const int mt = wm * 3 + mi;
      const int arow = mt * 16 + lm;
      const char* ab = lds + A_OFF + arow * 256;
      const int sa = (arow & 7) << 4;
      f32x4 acc0 = {0.f, 0.f, 0.f, 0.f};
      f32x4 acc1 = {0.f, 0.f, 0.f, 0.f};
      #pragma unroll
      for (int kk = 0; kk < 4; ++kk) {
        const int cb = kk * 64 + g * 16;   // same k-order as wupk layout
        short8 a = *(const short8*)(ab + (cb ^ sa));
        acc0 = __builtin_amdgcn_mfma_f32_16x16x32_bf16(a, bf0[kk], acc0, 0, 0, 0);
        acc1 = __builtin_amdgcn_mfma_f32_16x16x32_bf16(a, bf1[kk], acc1, 0, 0, 0);
      }
      #pragma unroll
      for (int r = 0; r < 4; ++r) {
        float v = sigf(acc0[r] + bfva) * wea + sigf(acc1[r] + bfvb) * web;
        v += __shfl_xor(v, 1);
        v += __shfl_xor(v, 2);
        v += __shfl_xor(v, 4);
        v += __shfl_xor(v, 8);
        if (lm == 0) ep[wh][o][mt * 16 + g * 4 + r] = v;  // C/D: row=(l>>4)*4+r
      }
    }
  }
  __syncthreads();

  // ---- softmax per order (wave o handles order o, rows >= 91 masked)
  if (w < 3) {
    const int o = w;
    const int n1 = l, n2 = l + 64;
    float e1 = -1e30f, e2 = -1e30f;
    if (n1 < NPG) e1 = ep[0][o][n1] + ep[1][o][n1] + ep[2][o][n1] + ep[3][o][n1];
    if (n2 < NPG) e2 = ep[0][o][n2] + ep[1][o][n2] + ep[2][o][n2] + ep[3][o][n2];
    float mx = fmaxf(e1, e2);
    #pragma unroll
    for (int m = 1; m < 64; m <<= 1) mx = fmaxf(mx, __shfl_xor(mx, m));
    float x1 = (n1 < NPG) ? __expf(e1 - mx) : 0.f;
    float x2 = (n2 < NPG) ? __expf(e2 - mx) : 0.f;
    float s = x1 + x2;
    #pragma unroll
    for (int m = 1; m < 64; m <<= 1) s += __shfl_xor(s, m);
    float inv = __builtin_amdgcn_rcpf(s);
    if (n1 < NPG) alpha[o][n1] = x1 * inv;
    if (n2 < NPG) alpha[o][n2] = x2 * inv;
  }
  __syncthreads();

  // ---- weighted sum: float4 loads, 16-way node-parallel; part overlays A region
  {
    const int n_off = t >> 5;           // 0..15
    const int d4 = (t & 31) * 4;
    float a0x = 0.f, a0y = 0.f, a0z = 0.f, a0w = 0.f;
    float a1x = 0.f, a1y = 0.f, a1z = 0.f, a1w = 0.f;
    float a2x = 0.f, a2y = 0.f, a2z = 0.f, a2w = 0.f;
    for (int n = n_off; n < NPG; n += 16) {
      float4 f = *(const float4*)(fbase + n * D + d4);
      float al0 = alpha[0][n], al1 = alpha[1][n], al2 = alpha[2][n];
      a0x += f.x * al0; a0y += f.y * al0; a0z += f.z * al0; a0w += f.w * al0;
      a1x += f.x * al1; a1y += f.y * al1; a1z += f.z * al1; a1w += f.w * al1;
      a2x += f.x * al2; a2y += f.y * al2; a2z += f.z * al2; a2w += f.w * al2;
    }
    float* part = (float*)(lds + A_OFF);   // [16][384], overlays dead A tile
    float4 s0 = {a0x, a0y, a0z, a0w};
    float4 s1 = {a1x, a1y, a1z, a1w};
    float4 s2 = {a2x, a2y, a2z, a2w};
    *(float4*)&part[n_off * 384 + 0 * 128 + d4] = s0;
    *(float4*)&part[n_off * 384 + 1 * 128 + d4] = s1;
    *(float4*)&part[n_off * 384 + 2 * 128 + d4] = s2;
  }
  __syncthreads();
  if (t < 384) {
    const float* part = (const float*)(lds + A_OFF);
    float s = 0.f;
    #pragma unroll
    for (int j = 0; j < 16; ++j) s += part[j * 384 + t];
    out[(size_t)b * 384 + t] = s;
  }
}

extern "C" void kernel_launch(void* const* d_in, const int* in_sizes, int n_in,
                              void* d_out, int out_size, void* d_ws, size_t ws_size,
                              hipStream_t stream) {
  const float* feats    = (const float*)d_in[0];
  const float* Wu       = (const float*)d_in[1];
  const float* bu       = (const float*)d_in[2];
  const float* Wv       = (const float*)d_in[3];
  const float* We       = (const float*)d_in[4];
  const int*   last_idx = (const int*)d_in[6];
  float* out = (float*)d_out;
  float* fvb  = (float*)d_ws;                              // 3*2048*128 f32 = 3 MB
  uint4* wupk = (uint4*)((char*)d_ws + 3 * NB * D * 4);    // 96 KB

  dim3 g0(128, 3);
  fv_kernel<<<g0, 256, 0, stream>>>(feats, Wv, bu, last_idx, fvb);
  wut_pack<<<12, 256, 0, stream>>>(Wu, wupk);
  sihg_main<<<NB, 512, 0, stream>>>(feats, wupk, We, fvb, out);
}

// Round 5
// 92.570 us; speedup vs baseline: 1.1712x; 1.1712x over previous
//
#include <hip/hip_runtime.h>
#include <hip/hip_bf16.h>
#include <stdint.h>

#define NB 2048      // groups
#define D 128
#define NPG 91
#define ROWS 96

typedef __attribute__((ext_vector_type(8))) short short8;
typedef __attribute__((ext_vector_type(4))) float f32x4;

__device__ __forceinline__ unsigned bf16pk(float a, float b) {
  __hip_bfloat162 h2 = __float22bfloat162_rn(make_float2(a, b));
  return *reinterpret_cast<unsigned*>(&h2);   // v_cvt_pk_bf16_f32
}

__device__ __forceinline__ float sigf(float x) {
  float e = __expf(-x);
  return __builtin_amdgcn_rcpf(1.0f + e);     // v_rcp_f32, ~1ulp
}

// K0a: fv[o][b][h] = sum_d feats[last_idx[o][b]][d] * Wv[o][d][h]  + bu[o][h]
__global__ void fv_kernel(const float* __restrict__ feats,
                          const float* __restrict__ Wv,
                          const float* __restrict__ bu,
                          const int* __restrict__ last_idx,
                          float* __restrict__ fv) {
  __shared__ float rows[16][128];
  __shared__ int lidx[16];
  const int o = blockIdx.y;
  const int b0 = blockIdx.x * 16;
  const int t = threadIdx.x;
  if (t < 16) lidx[t] = last_idx[o * NB + b0 + t];
  __syncthreads();
  #pragma unroll
  for (int i = 0; i < 8; ++i) {
    int el = t + i * 256;
    int r = el >> 7, d = el & 127;
    rows[r][d] = feats[(size_t)lidx[r] * D + d];
  }
  __syncthreads();
  const int h = t & 127, half = t >> 7;
  float acc[8];
  #pragma unroll
  for (int j = 0; j < 8; ++j) acc[j] = 0.f;
  const float* wvo = Wv + (size_t)o * D * D + h;
  for (int d0 = 0; d0 < D; d0 += 4) {
    float w0 = wvo[(d0 + 0) * D], w1 = wvo[(d0 + 1) * D];
    float w2 = wvo[(d0 + 2) * D], w3 = wvo[(d0 + 3) * D];
    #pragma unroll
    for (int j = 0; j < 8; ++j) {
      const float4 f = *(const float4*)&rows[half * 8 + j][d0];
      acc[j] += f.x * w0 + f.y * w1 + f.z * w2 + f.w * w3;
    }
  }
  const float bb = bu[o * D + h];
  #pragma unroll
  for (int j = 0; j < 8; ++j)
    fv[((size_t)o * NB + b0 + half * 8 + j) * D + h] = acc[j] + bb;
}

// K0b: pack Wu transposed to bf16 in MFMA B-fragment order:
// wupk[(o*4+kk)*512 + row*4 + g] (uint4) = Wu[o][kk*32+g*8 + 0..7][row] as 8 bf16
__global__ void wut_pack(const float* __restrict__ Wu, uint4* __restrict__ wupk) {
  const int o = blockIdx.x >> 2, kk = blockIdx.x & 3;
  const int t = threadIdx.x;
  #pragma unroll
  for (int i = 0; i < 2; ++i) {
    int idx = i * 256 + t;              // 0..511
    int row = idx >> 2, g = idx & 3;
    const float* src = Wu + (size_t)o * D * D + (kk * 32 + g * 8) * D + row;
    uint4 pk;
    pk.x = bf16pk(src[0 * D], src[1 * D]);
    pk.y = bf16pk(src[2 * D], src[3 * D]);
    pk.z = bf16pk(src[4 * D], src[5 * D]);
    pk.w = bf16pk(src[6 * D], src[7 * D]);
    wupk[(size_t)blockIdx.x * 512 + idx] = pk;
  }
}

// K1: one block per group, 512 threads (8 waves), 6 waves/EU cap (no spill).
// Wave (wm,wh): M-half wm (3 of 6 M-tiles) x h-slice wh (32 of 128 h).
__global__ __launch_bounds__(512, 6) void sihg_main(
    const float* __restrict__ feats,
    const uint4* __restrict__ wupk,
    const float* __restrict__ We,
    const float* __restrict__ fvb,
    float* __restrict__ out) {
  __shared__ __align__(16) char lds[30336];
  constexpr int A_OFF  = 0;       // bf16 [96][128] swizzled (256B rows); later part[16][384] f32
  constexpr int EP_OFF = 24576;   // float [4][3][96] e-partials (indexed by wh)
  constexpr int AL_OFF = 29184;   // float [3][96]

  const int t = threadIdx.x;
  const int b = blockIdx.x;
  const int w = t >> 6;       // wave 0..7
  const int wh = w & 3;       // h-slice
  const int wm = w >> 2;      // M-half
  const int l = t & 63;
  const int g = l >> 4;
  const int lm = l & 15;

  float (*ep)[3][96] = (float (*)[3][96])(lds + EP_OFF);
  float (*alpha)[96] = (float (*)[96])(lds + AL_OFF);

  const float* fbase = feats + (size_t)b * NPG * D;
  const int h1 = 32 * wh + lm, h2 = 32 * wh + 16 + lm;

  // ---- phase 1: feats -> LDS bf16, swizzled; rows 91..95 zero-padded
  #pragma unroll
  for (int i = 0; i < 3; ++i) {
    int c = t + i * 512;              // 1536 chunks of 8 bf16
    int r = c >> 4, d0 = (c & 15) * 8;
    uint4 pk4;
    if (r < NPG) {
      const float* src = fbase + r * D + d0;
      float4 f0 = *(const float4*)(src);
      float4 f1 = *(const float4*)(src + 4);
      pk4.x = bf16pk(f0.x, f0.y);
      pk4.y = bf16pk(f0.z, f0.w);
      pk4.z = bf16pk(f1.x, f1.y);
      pk4.w = bf16pk(f1.z, f1.w);
    } else {
      pk4.x = 0u; pk4.y = 0u; pk4.z = 0u; pk4.w = 0u;
    }
    int off = r * 256 + ((d0 * 2) ^ ((r & 7) << 4));
    *(uint4*)(lds + A_OFF + off) = pk4;
  }
  __syncthreads();

  for (int o = 0; o < 3; ++o) {
    short8 bf0[4], bf1[4];
    #pragma unroll
    for (int kk = 0; kk < 4; ++kk) {
      size_t base = (size_t)(o * 4 + kk) * 512;
      bf0[kk] = *(const short8*)&wupk[base + h1 * 4 + g];
      bf1[kk] = *(const short8*)&wupk[base + h2 * 4 + g];
    }
    const float bfva = fvb[((size_t)o * NB + b) * D + h1];
    const float bfvb = fvb[((size_t)o * NB + b) * D + h2];
    const float wea  = We[o * D + h1];
    const float web  = We[o * D + h2];

    #pragma unroll
    for (int mi = 0; mi < 3; ++mi) {
      const int mt = wm * 3 + mi;
      const int arow = mt * 16 + lm;
      const char* ab = lds + A_OFF + arow * 256;
      const int sa = (arow & 7) << 4;
      f32x4 acc0 = {0.f, 0.f, 0.f, 0.f};
      f32x4 acc1 = {0.f, 0.f, 0.f, 0.f};
      #pragma unroll
      for (int kk = 0; kk < 4; ++kk) {
        const int cb = kk * 64 + g * 16;   // same k-order as wupk layout
        short8 a = *(const short8*)(ab + (cb ^ sa));
        acc0 = __builtin_amdgcn_mfma_f32_16x16x32_bf16(a, bf0[kk], acc0, 0, 0, 0);
        acc1 = __builtin_amdgcn_mfma_f32_16x16x32_bf16(a, bf1[kk], acc1, 0, 0, 0);
      }
      #pragma unroll
      for (int r = 0; r < 4; ++r) {
        float v = sigf(acc0[r] + bfva) * wea + sigf(acc1[r] + bfvb) * web;
        v += __shfl_xor(v, 1);
        v += __shfl_xor(v, 2);
        v += __shfl_xor(v, 4);
        v += __shfl_xor(v, 8);
        if (lm == 0) ep[wh][o][mt * 16 + g * 4 + r] = v;  // C/D: row=(l>>4)*4+r
      }
    }
  }
  __syncthreads();

  // ---- softmax per order (wave o handles order o, rows >= 91 masked)
  if (w < 3) {
    const int o = w;
    const int n1 = l, n2 = l + 64;
    float e1 = -1e30f, e2 = -1e30f;
    if (n1 < NPG) e1 = ep[0][o][n1] + ep[1][o][n1] + ep[2][o][n1] + ep[3][o][n1];
    if (n2 < NPG) e2 = ep[0][o][n2] + ep[1][o][n2] + ep[2][o][n2] + ep[3][o][n2];
    float mx = fmaxf(e1, e2);
    #pragma unroll
    for (int m = 1; m < 64; m <<= 1) mx = fmaxf(mx, __shfl_xor(mx, m));
    float x1 = (n1 < NPG) ? __expf(e1 - mx) : 0.f;
    float x2 = (n2 < NPG) ? __expf(e2 - mx) : 0.f;
    float s = x1 + x2;
    #pragma unroll
    for (int m = 1; m < 64; m <<= 1) s += __shfl_xor(s, m);
    float inv = __builtin_amdgcn_rcpf(s);
    if (n1 < NPG) alpha[o][n1] = x1 * inv;
    if (n2 < NPG) alpha[o][n2] = x2 * inv;
  }
  __syncthreads();

  // ---- weighted sum: float4 loads, 16-way node-parallel; part overlays A region
  {
    const int n_off = t >> 5;           // 0..15
    const int d4 = (t & 31) * 4;
    float a0x = 0.f, a0y = 0.f, a0z = 0.f, a0w = 0.f;
    float a1x = 0.f, a1y = 0.f, a1z = 0.f, a1w = 0.f;
    float a2x = 0.f, a2y = 0.f, a2z = 0.f, a2w = 0.f;
    for (int n = n_off; n < NPG; n += 16) {
      float4 f = *(const float4*)(fbase + n * D + d4);
      float al0 = alpha[0][n], al1 = alpha[1][n], al2 = alpha[2][n];
      a0x += f.x * al0; a0y += f.y * al0; a0z += f.z * al0; a0w += f.w * al0;
      a1x += f.x * al1; a1y += f.y * al1; a1z += f.z * al1; a1w += f.w * al1;
      a2x += f.x * al2; a2y += f.y * al2; a2z += f.z * al2; a2w += f.w * al2;
    }
    float* part = (float*)(lds + A_OFF);   // [16][384], overlays dead A tile
    float4 s0 = {a0x, a0y, a0z, a0w};
    float4 s1 = {a1x, a1y, a1z, a1w};
    float4 s2 = {a2x, a2y, a2z, a2w};
    *(float4*)&part[n_off * 384 + 0 * 128 + d4] = s0;
    *(float4*)&part[n_off * 384 + 1 * 128 + d4] = s1;
    *(float4*)&part[n_off * 384 + 2 * 128 + d4] = s2;
  }
  __syncthreads();
  if (t < 384) {
    const float* part = (const float*)(lds + A_OFF);
    float s = 0.f;
    #pragma unroll
    for (int j = 0; j < 16; ++j) s += part[j * 384 + t];
    out[(size_t)b * 384 + t] = s;
  }
}

extern "C" void kernel_launch(void* const* d_in, const int* in_sizes, int n_in,
                              void* d_out, int out_size, void* d_ws, size_t ws_size,
                              hipStream_t stream) {
  const float* feats    = (const float*)d_in[0];
  const float* Wu       = (const float*)d_in[1];
  const float* bu       = (const float*)d_in[2];
  const float* Wv       = (const float*)d_in[3];
  const float* We       = (const float*)d_in[4];
  const int*   last_idx = (const int*)d_in[6];
  float* out = (float*)d_out;
  float* fvb  = (float*)d_ws;                              // 3*2048*128 f32 = 3 MB
  uint4* wupk = (uint4*)((char*)d_ws + 3 * NB * D * 4);    // 96 KB

  dim3 g0(128, 3);
  fv_kernel<<<g0, 256, 0, stream>>>(feats, Wv, bu, last_idx, fvb);
  wut_pack<<<12, 256, 0, stream>>>(Wu, wupk);
  sihg_main<<<NB, 512, 0, stream>>>(feats, wupk, We, fvb, out);
}

// Round 6
// 83.225 us; speedup vs baseline: 1.3027x; 1.1123x over previous
//
#include <hip/hip_runtime.h>
#include <hip/hip_bf16.h>
#include <stdint.h>

#define NB 2048      // groups
#define D 128
#define NPG 91
#define ROWS 96

typedef __attribute__((ext_vector_type(8))) short short8;
typedef __attribute__((ext_vector_type(4))) float f32x4;

__device__ __forceinline__ unsigned bf16pk(float a, float b) {
  __hip_bfloat162 h2 = __float22bfloat162_rn(make_float2(a, b));
  return *reinterpret_cast<unsigned*>(&h2);   // v_cvt_pk_bf16_f32
}

__device__ __forceinline__ float sigf(float x) {
  float e = __expf(-x);
  return __builtin_amdgcn_rcpf(1.0f + e);     // v_rcp_f32, ~1ulp
}

// K0a: fv[o][b][h] = sum_d feats[last_idx[o][b]][d] * Wv[o][d][h]  + bu[o][h]
__global__ void fv_kernel(const float* __restrict__ feats,
                          const float* __restrict__ Wv,
                          const float* __restrict__ bu,
                          const int* __restrict__ last_idx,
                          float* __restrict__ fv) {
  __shared__ float rows[16][128];
  __shared__ int lidx[16];
  const int o = blockIdx.y;
  const int b0 = blockIdx.x * 16;
  const int t = threadIdx.x;
  if (t < 16) lidx[t] = last_idx[o * NB + b0 + t];
  __syncthreads();
  #pragma unroll
  for (int i = 0; i < 8; ++i) {
    int el = t + i * 256;
    int r = el >> 7, d = el & 127;
    rows[r][d] = feats[(size_t)lidx[r] * D + d];
  }
  __syncthreads();
  const int h = t & 127, half = t >> 7;
  float acc[8];
  #pragma unroll
  for (int j = 0; j < 8; ++j) acc[j] = 0.f;
  const float* wvo = Wv + (size_t)o * D * D + h;
  for (int d0 = 0; d0 < D; d0 += 4) {
    float w0 = wvo[(d0 + 0) * D], w1 = wvo[(d0 + 1) * D];
    float w2 = wvo[(d0 + 2) * D], w3 = wvo[(d0 + 3) * D];
    #pragma unroll
    for (int j = 0; j < 8; ++j) {
      const float4 f = *(const float4*)&rows[half * 8 + j][d0];
      acc[j] += f.x * w0 + f.y * w1 + f.z * w2 + f.w * w3;
    }
  }
  const float bb = bu[o * D + h];
  #pragma unroll
  for (int j = 0; j < 8; ++j)
    fv[((size_t)o * NB + b0 + half * 8 + j) * D + h] = acc[j] + bb;
}

// K0b: pack Wu into pre-swizzled A-fragment LDS images (flipped GEMM: A = WuT).
// Unit u = o*2 + kh (K-half). Image: 1024 uint4 (16 KB):
//   img[h*8 + (s ^ (h&7))] = 8 bf16 of Wu[o][d = kh*64 + (s>>2)*32 + (s&3)*8 + j][h]
// so the main kernel stages with a PURE LINEAR copy and reads with the XOR swizzle.
__global__ void wut_pack(const float* __restrict__ Wu, uint4* __restrict__ wupk) {
  const int o = blockIdx.x >> 1, kh = blockIdx.x & 1;
  const int t = threadIdx.x;
  #pragma unroll
  for (int i = 0; i < 4; ++i) {
    int idx = i * 256 + t;            // 0..1023
    int h = idx >> 3, s = idx & 7;
    int d0 = kh * 64 + (s >> 2) * 32 + (s & 3) * 8;
    const float* src = Wu + (size_t)o * D * D + (size_t)d0 * D + h;
    uint4 pk;
    pk.x = bf16pk(src[0 * D], src[1 * D]);
    pk.y = bf16pk(src[2 * D], src[3 * D]);
    pk.z = bf16pk(src[4 * D], src[5 * D]);
    pk.w = bf16pk(src[6 * D], src[7 * D]);
    wupk[(size_t)blockIdx.x * 1024 + h * 8 + (s ^ (h & 7))] = pk;
  }
}

// K1: one block per group, 384 threads / 6 waves; wave = one 16-node tile.
// Flipped MFMA: D[row=h][col=node] -> e-reduce over h is in-lane + 2 shfl.
__global__ __launch_bounds__(384, 4) void sihg_main(
    const float* __restrict__ feats,
    const uint4* __restrict__ wupk,
    const float* __restrict__ We,
    const float* __restrict__ fvb,
    float* __restrict__ out) {
  __shared__ __align__(16) char lds[45312];
  constexpr int WUT_OFF = 0;      // 16384: WuT K-half image (pre-swizzled)
  constexpr int A_OFF   = 16384;  // 24576: feats bf16 [96] x 256B swizzled; later part[12][384] f32
  constexpr int BFV_OFF = 40960;  // 512:  f32[128]  (fv+bu for current order)
  constexpr int WEL_OFF = 41472;  // 1536: f32[3][128]
  constexpr int E_OFF   = 43008;  // 1152: f32[3][96]
  constexpr int AL_OFF  = 44160;  // 1152: f32[3][96]

  const int t = threadIdx.x;
  const int b = blockIdx.x;
  const int nt = t >> 6;      // wave = node-tile 0..5
  const int l = t & 63;
  const int g = l >> 4;
  const int lm = l & 15;

  uint4* wut = (uint4*)(lds + WUT_OFF);
  float* bfvp = (float*)(lds + BFV_OFF);
  float* wel = (float*)(lds + WEL_OFF);
  float* e_lds = (float*)(lds + E_OFF);
  float (*alpha)[96] = (float (*)[96])(lds + AL_OFF);

  const float* fbase = feats + (size_t)b * NPG * D;

  // stage-pipeline registers
  uint4 r0, r1, r2;
  float sb = 0.f;

#define LOAD_UNIT(u_, SB, o_) do {                                        \
    int base_ = (u_) * 1024;                                              \
    r0 = wupk[base_ + t];                                                 \
    r1 = wupk[base_ + 384 + t];                                           \
    if (t < 256) r2 = wupk[base_ + 768 + t];                              \
    if ((SB) && t < 128) sb = fvb[((size_t)(o_) * NB + b) * D + t];       \
  } while (0)

#define WRITE_UNIT(SB) do {                                               \
    wut[t] = r0;                                                          \
    wut[384 + t] = r1;                                                    \
    if (t < 256) wut[768 + t] = r2;                                       \
    if ((SB) && t < 128) bfvp[t] = sb;                                    \
  } while (0)

  // ---- feats -> LDS bf16, swizzled; rows 91..95 zero-padded
  #pragma unroll
  for (int i = 0; i < 4; ++i) {
    int c = t + i * 384;              // 1536 chunks of 8 bf16
    int r = c >> 4, d0 = (c & 15) * 8;
    uint4 pk4;
    if (r < NPG) {
      const float* src = fbase + r * D + d0;
      float4 f0 = *(const float4*)(src);
      float4 f1 = *(const float4*)(src + 4);
      pk4.x = bf16pk(f0.x, f0.y);
      pk4.y = bf16pk(f0.z, f0.w);
      pk4.z = bf16pk(f1.x, f1.y);
      pk4.w = bf16pk(f1.z, f1.w);
    } else {
      pk4.x = 0u; pk4.y = 0u; pk4.z = 0u; pk4.w = 0u;
    }
    int off = r * 256 + ((d0 * 2) ^ ((r & 7) << 4));
    *(uint4*)(lds + A_OFF + off) = pk4;
  }
  wel[t] = We[t];                     // 3*128 = 384 floats

  // prologue: unit0 (o=0,kh=0) + bfv0 staged; unit1 regs in flight
  LOAD_UNIT(0, true, 0);
  WRITE_UNIT(true);
  LOAD_UNIT(1, false, 0);
  __syncthreads();                    // feats + wel + unit0 + bfv0 visible

  // B-fragments (feats) for this wave's node-tile, order-invariant
  short8 bf[4];
  {
    const int row = nt * 16 + lm;
    const char* ab = lds + A_OFF + row * 256;
    const int sa = (row & 7) << 4;
    #pragma unroll
    for (int kk = 0; kk < 4; ++kk)
      bf[kk] = *(const short8*)(ab + ((kk * 64 + g * 16) ^ sa));
  }

  #pragma unroll
  for (int o = 0; o < 3; ++o) {
    f32x4 acc[8];
    // ---- K-half 0 (unit 2o, already in LDS)
    #pragma unroll
    for (int ht = 0; ht < 8; ++ht) {
      const int row = ht * 16 + lm;
      const char* abase = lds + WUT_OFF + row * 128;
      const int q = (row & 7);
      short8 a0 = *(const short8*)(abase + (((0 * 4 + g) ^ q) << 4));
      short8 a1 = *(const short8*)(abase + (((1 * 4 + g) ^ q) << 4));
      f32x4 z = {0.f, 0.f, 0.f, 0.f};
      acc[ht] = __builtin_amdgcn_mfma_f32_16x16x32_bf16(a0, bf[0], z, 0, 0, 0);
      acc[ht] = __builtin_amdgcn_mfma_f32_16x16x32_bf16(a1, bf[1], acc[ht], 0, 0, 0);
    }
    __syncthreads();                  // all waves done reading unit 2o
    WRITE_UNIT(false);                // unit 2o+1
    if (o < 2) LOAD_UNIT(2 * o + 2, true, o + 1);
    __syncthreads();                  // unit 2o+1 visible

    // ---- K-half 1 (unit 2o+1) + fused epilogue
    float e_part = 0.f;
    #pragma unroll
    for (int ht = 0; ht < 8; ++ht) {
      const int row = ht * 16 + lm;
      const char* abase = lds + WUT_OFF + row * 128;
      const int q = (row & 7);
      short8 a2 = *(const short8*)(abase + (((0 * 4 + g) ^ q) << 4));
      short8 a3 = *(const short8*)(abase + (((1 * 4 + g) ^ q) << 4));
      acc[ht] = __builtin_amdgcn_mfma_f32_16x16x32_bf16(a2, bf[2], acc[ht], 0, 0, 0);
      acc[ht] = __builtin_amdgcn_mfma_f32_16x16x32_bf16(a3, bf[3], acc[ht], 0, 0, 0);
      // bias + sigmoid + We, broadcast b128 reads (h = ht*16 + g*4 + r)
      f32x4 bb = *(const f32x4*)(lds + BFV_OFF + (ht * 16 + g * 4) * 4);
      f32x4 ww = *(const f32x4*)(lds + WEL_OFF + o * 512 + (ht * 16 + g * 4) * 4);
      #pragma unroll
      for (int r = 0; r < 4; ++r)
        e_part += sigf(acc[ht][r] + bb[r]) * ww[r];
    }
    // reduce over g-groups (h) : 2 shfls only
    e_part += __shfl_xor(e_part, 16);
    e_part += __shfl_xor(e_part, 32);
    if (l < 16) e_lds[o * 96 + nt * 16 + l] = e_part;

    if (o < 2) {
      __syncthreads();                // done reading unit 2o+1 (+ bfv[o])
      WRITE_UNIT(true);               // unit 2o+2 + bfv[o+1]
      LOAD_UNIT(2 * o + 3, false, 0);
      __syncthreads();                // visible
    }
  }
  __syncthreads();

  // ---- softmax per order (wave o handles order o, rows >= 91 masked)
  const int w = nt;
  if (w < 3) {
    const int o = w;
    const int n1 = l, n2 = l + 64;
    float e1 = -1e30f, e2 = -1e30f;
    if (n1 < NPG) e1 = e_lds[o * 96 + n1];
    if (n2 < NPG) e2 = e_lds[o * 96 + n2];
    float mx = fmaxf(e1, e2);
    #pragma unroll
    for (int m = 1; m < 64; m <<= 1) mx = fmaxf(mx, __shfl_xor(mx, m));
    float x1 = (n1 < NPG) ? __expf(e1 - mx) : 0.f;
    float x2 = (n2 < NPG) ? __expf(e2 - mx) : 0.f;
    float s = x1 + x2;
    #pragma unroll
    for (int m = 1; m < 64; m <<= 1) s += __shfl_xor(s, m);
    float inv = __builtin_amdgcn_rcpf(s);
    if (n1 < NPG) alpha[o][n1] = x1 * inv;
    if (n2 < NPG) alpha[o][n2] = x2 * inv;
  }
  __syncthreads();

  // ---- weighted sum: float4 loads, 12-way node-parallel; part overlays feats LDS
  {
    const int n_off = t >> 5;           // 0..11
    const int d4 = (t & 31) * 4;
    float a0x = 0.f, a0y = 0.f, a0z = 0.f, a0w = 0.f;
    float a1x = 0.f, a1y = 0.f, a1z = 0.f, a1w = 0.f;
    float a2x = 0.f, a2y = 0.f, a2z = 0.f, a2w = 0.f;
    for (int n = n_off; n < NPG; n += 12) {
      float4 f = *(const float4*)(fbase + n * D + d4);
      float al0 = alpha[0][n], al1 = alpha[1][n], al2 = alpha[2][n];
      a0x += f.x * al0; a0y += f.y * al0; a0z += f.z * al0; a0w += f.w * al0;
      a1x += f.x * al1; a1y += f.y * al1; a1z += f.z * al1; a1w += f.w * al1;
      a2x += f.x * al2; a2y += f.y * al2; a2z += f.z * al2; a2w += f.w * al2;
    }
    float* part = (float*)(lds + A_OFF);   // [12][384] f32
    float4 s0 = {a0x, a0y, a0z, a0w};
    float4 s1 = {a1x, a1y, a1z, a1w};
    float4 s2 = {a2x, a2y, a2z, a2w};
    *(float4*)&part[n_off * 384 + 0 * 128 + d4] = s0;
    *(float4*)&part[n_off * 384 + 1 * 128 + d4] = s1;
    *(float4*)&part[n_off * 384 + 2 * 128 + d4] = s2;
  }
  __syncthreads();
  {
    const float* part = (const float*)(lds + A_OFF);
    float s = 0.f;
    #pragma unroll
    for (int j = 0; j < 12; ++j) s += part[j * 384 + t];
    out[(size_t)b * 384 + t] = s;
  }
#undef LOAD_UNIT
#undef WRITE_UNIT
}

extern "C" void kernel_launch(void* const* d_in, const int* in_sizes, int n_in,
                              void* d_out, int out_size, void* d_ws, size_t ws_size,
                              hipStream_t stream) {
  const float* feats    = (const float*)d_in[0];
  const float* Wu       = (const float*)d_in[1];
  const float* bu       = (const float*)d_in[2];
  const float* Wv       = (const float*)d_in[3];
  const float* We       = (const float*)d_in[4];
  const int*   last_idx = (const int*)d_in[6];
  float* out = (float*)d_out;
  float* fvb  = (float*)d_ws;                              // 3*2048*128 f32 = 3 MB
  uint4* wupk = (uint4*)((char*)d_ws + 3 * NB * D * 4);    // 96 KB

  dim3 g0(128, 3);
  fv_kernel<<<g0, 256, 0, stream>>>(feats, Wv, bu, last_idx, fvb);
  wut_pack<<<6, 256, 0, stream>>>(Wu, wupk);
  sihg_main<<<NB, 384, 0, stream>>>(feats, wupk, We, fvb, out);
}